// Round 1
// baseline (133.583 us; speedup 1.0000x reference)
//
#include <hip/hip_runtime.h>

#define ACN_EPS   0.001f
#define ACN_LOG2E 1.4426950408889634f

// ---------------------------------------------------------------------------
// Setup: compute per-component constants from mean/variance/prior (K=8).
//   P[0..7]   = mu_k
//   P[8..15]  = s1_k = -0.5*log2(e)/v_k^2              (denom exponent scale)
//   P[16..23] = s2_k = -0.5*log2(e)/(v_k+eps)^2        (out exponent scale)
//   P[24..31] = lp_k = log2(p_k)                       (prior folded into exp2)
//   P[32..39] = lw_k = log2(p_k/(sqrt(p_k+eps)*sqrt(v_k+eps)))
// One wave; each group of 8 lanes replicates the 8-way softmax via shfl_xor.
// ---------------------------------------------------------------------------
__global__ void acn_setup(const float* __restrict__ mean,
                          const float* __restrict__ variance,
                          const float* __restrict__ prior,
                          float* __restrict__ P) {
    int lane = threadIdx.x;
    int k = lane & 7;
    float m  = mean[k];
    float va = variance[k];
    float p0 = prior[k];

    float v = logf(1.0f + expf(va));               // softplus
    // softmax over the 8 priors (replicated in each group of 8 lanes)
    float mx = p0;
    for (int off = 1; off < 8; off <<= 1) mx = fmaxf(mx, __shfl_xor(mx, off, 64));
    float e = expf(p0 - mx);
    float sum = e;
    for (int off = 1; off < 8; off <<= 1) sum += __shfl_xor(sum, off, 64);
    float pk = e / sum;

    float s1 = -0.5f * ACN_LOG2E / (v * v);
    float ve = v + ACN_EPS;
    float s2 = -0.5f * ACN_LOG2E / (ve * ve);
    float lp = log2f(pk);
    float lw = lp - 0.5f * log2f(pk + ACN_EPS) - 0.5f * log2f(ve);

    if (lane < 8) {
        P[k]      = m;
        P[8 + k]  = s1;
        P[16 + k] = s2;
        P[24 + k] = lp;
        P[32 + k] = lw;
    }
}

// ---------------------------------------------------------------------------
// Main: elementwise, float4-vectorized, grid-stride.
// out = r * sum_k exp2(s2_k*d^2 + lw_k) * d,  r = 1/(denom+eps),
// denom = sum_k exp2(s1_k*d^2 + lp_k),        d = x - mu_k
// ---------------------------------------------------------------------------
__device__ __forceinline__ float acn_elem(float x,
                                          const float* mu, const float* s1,
                                          const float* s2, const float* lp,
                                          const float* lw) {
    float denom = 0.0f, S = 0.0f;
#pragma unroll
    for (int k = 0; k < 8; ++k) {
        float d  = x - mu[k];
        float d2 = d * d;
        denom += __builtin_amdgcn_exp2f(fmaf(s1[k], d2, lp[k]));
        S = fmaf(__builtin_amdgcn_exp2f(fmaf(s2[k], d2, lw[k])), d, S);
    }
    return S * __builtin_amdgcn_rcpf(denom + ACN_EPS);
}

__global__ __launch_bounds__(256) void acn_main(const float4* __restrict__ x,
                                                float4* __restrict__ out,
                                                const float* __restrict__ P,
                                                int n4) {
    float mu[8], s1[8], s2[8], lp[8], lw[8];
#pragma unroll
    for (int k = 0; k < 8; ++k) {
        mu[k] = P[k];
        s1[k] = P[8 + k];
        s2[k] = P[16 + k];
        lp[k] = P[24 + k];
        lw[k] = P[32 + k];
    }

    int idx    = blockIdx.x * blockDim.x + threadIdx.x;
    int stride = gridDim.x * blockDim.x;
    for (int i = idx; i < n4; i += stride) {
        float4 xv = x[i];
        float4 ov;
        ov.x = acn_elem(xv.x, mu, s1, s2, lp, lw);
        ov.y = acn_elem(xv.y, mu, s1, s2, lp, lw);
        ov.z = acn_elem(xv.z, mu, s1, s2, lp, lw);
        ov.w = acn_elem(xv.w, mu, s1, s2, lp, lw);
        out[i] = ov;
    }
}

extern "C" void kernel_launch(void* const* d_in, const int* in_sizes, int n_in,
                              void* d_out, int out_size, void* d_ws, size_t ws_size,
                              hipStream_t stream) {
    const float* x        = (const float*)d_in[0];
    const float* mean     = (const float*)d_in[1];
    const float* variance = (const float*)d_in[2];
    const float* prior    = (const float*)d_in[3];
    float* out = (float*)d_out;
    float* P   = (float*)d_ws;   // 40 floats of per-component constants

    acn_setup<<<1, 64, 0, stream>>>(mean, variance, prior, P);

    int n4 = out_size / 4;       // out_size = 16,777,216, divisible by 4
    const int block = 256;
    const int grid  = 4096;      // 1M threads, 4 float4 iters each (grid-stride)
    acn_main<<<grid, block, 0, stream>>>((const float4*)x, (float4*)out, P, n4);
}

// Round 2
// 129.051 us; speedup vs baseline: 1.0351x; 1.0351x over previous
//
#include <hip/hip_runtime.h>

#define ACN_EPS   0.001f
#define ACN_LOG2E 1.4426950408889634f
#define ACN_LN2   0.6931471805599453f

typedef float v4f __attribute__((ext_vector_type(4)));

// ---------------------------------------------------------------------------
// Setup (K=8). P layout (stride 8):
//   P[0..7]   mu_k
//   P[8..15]  s1_k  = -0.5*log2(e)/v^2            (denom exponent scale)
//   P[16..23] lp_k  = log2(p_k)
//   P[24..31] ds_k  = (s2-s1)*ln2                  (ratio-poly argument scale)
//   P[32..39] c0_k  = C = 1/sqrt((p_k+eps)*(v+eps))   [= c1]
//   P[40..47] c2_k  = C/2
//   P[48..55] c3_k  = C/6
// Identity: exp2(s2*d^2+lw) = exp2(s1*d^2+lp) * C * e^u, u = ds*d^2 in [0,~0.13]
// e^u approximated by cubic Taylor (rel err <= u^4/24 ~ 1.2e-5).
// ---------------------------------------------------------------------------
__global__ void acn_setup(const float* __restrict__ mean,
                          const float* __restrict__ variance,
                          const float* __restrict__ prior,
                          float* __restrict__ P) {
    int lane = threadIdx.x;
    int k = lane & 7;
    float m  = mean[k];
    float va = variance[k];
    float p0 = prior[k];

    float v = logf(1.0f + expf(va));               // softplus
    // softmax over the 8 priors (replicated in each group of 8 lanes)
    float mx = p0;
    for (int off = 1; off < 8; off <<= 1) mx = fmaxf(mx, __shfl_xor(mx, off, 64));
    float e = expf(p0 - mx);
    float sum = e;
    for (int off = 1; off < 8; off <<= 1) sum += __shfl_xor(sum, off, 64);
    float pk = e / sum;

    float s1 = -0.5f * ACN_LOG2E / (v * v);
    float ve = v + ACN_EPS;
    float s2 = -0.5f * ACN_LOG2E / (ve * ve);
    float lp = log2f(pk);
    float C  = 1.0f / sqrtf((pk + ACN_EPS) * ve);
    float ds = (s2 - s1) * ACN_LN2;

    if (lane < 8) {
        P[k]      = m;
        P[8 + k]  = s1;
        P[16 + k] = lp;
        P[24 + k] = ds;
        P[32 + k] = C;
        P[40 + k] = C * 0.5f;
        P[48 + k] = C * (1.0f / 6.0f);
    }
}

// ---------------------------------------------------------------------------
// Main: 8 exps/element (was 16). Per element per k:
//   E = exp2(s1*d^2 + lp)           -> denom term
//   numerator term = E * d * Horner(u; C, C, C/2, C/6),  u = ds*d^2
// 4 elements interleaved (j-inner) for ILP / v_pk_fma SLP.
// ---------------------------------------------------------------------------
__global__ __launch_bounds__(256) void acn_main(const v4f* __restrict__ x,
                                                v4f* __restrict__ out,
                                                const float* __restrict__ P,
                                                int n4) {
    float mu[8], s1[8], lp[8], ds[8], c0[8], c2[8], c3[8];
#pragma unroll
    for (int k = 0; k < 8; ++k) {
        mu[k] = P[k];
        s1[k] = P[8 + k];
        lp[k] = P[16 + k];
        ds[k] = P[24 + k];
        c0[k] = P[32 + k];
        c2[k] = P[40 + k];
        c3[k] = P[48 + k];
    }

    int idx    = blockIdx.x * blockDim.x + threadIdx.x;
    int stride = gridDim.x * blockDim.x;
    for (int i = idx; i < n4; i += stride) {
        v4f xv = x[i];
        float xs[4]    = {xv.x, xv.y, xv.z, xv.w};
        float denom[4] = {0.0f, 0.0f, 0.0f, 0.0f};
        float S[4]     = {0.0f, 0.0f, 0.0f, 0.0f};
#pragma unroll
        for (int k = 0; k < 8; ++k) {
#pragma unroll
            for (int j = 0; j < 4; ++j) {
                float d  = xs[j] - mu[k];
                float d2 = d * d;
                float E  = __builtin_amdgcn_exp2f(fmaf(s1[k], d2, lp[k]));
                denom[j] += E;
                float u  = ds[k] * d2;
                float q  = fmaf(u, c3[k], c2[k]);
                q        = fmaf(q, u, c0[k]);
                q        = fmaf(q, u, c0[k]);
                S[j]     = fmaf(E * d, q, S[j]);
            }
        }
        v4f ov;
        ov.x = S[0] * __builtin_amdgcn_rcpf(denom[0] + ACN_EPS);
        ov.y = S[1] * __builtin_amdgcn_rcpf(denom[1] + ACN_EPS);
        ov.z = S[2] * __builtin_amdgcn_rcpf(denom[2] + ACN_EPS);
        ov.w = S[3] * __builtin_amdgcn_rcpf(denom[3] + ACN_EPS);
        __builtin_nontemporal_store(ov, &out[i]);
    }
}

extern "C" void kernel_launch(void* const* d_in, const int* in_sizes, int n_in,
                              void* d_out, int out_size, void* d_ws, size_t ws_size,
                              hipStream_t stream) {
    const float* x        = (const float*)d_in[0];
    const float* mean     = (const float*)d_in[1];
    const float* variance = (const float*)d_in[2];
    const float* prior    = (const float*)d_in[3];
    float* out = (float*)d_out;
    float* P   = (float*)d_ws;   // 56 floats of per-component constants

    acn_setup<<<1, 64, 0, stream>>>(mean, variance, prior, P);

    int n4 = out_size / 4;       // 4,194,304
    const int block = 256;
    const int grid  = 2048;      // 32 waves/CU exactly; 8 float4 iters/thread
    acn_main<<<grid, block, 0, stream>>>((const v4f*)x, (v4f*)out, P, n4);
}

// Round 3
// 123.799 us; speedup vs baseline: 1.0790x; 1.0424x over previous
//
#include <hip/hip_runtime.h>

#define ACN_EPS   0.001f
#define ACN_LOG2E 1.4426950408889634f
#define ACN_LN2   0.6931471805599453f

typedef float v2f __attribute__((ext_vector_type(2)));
typedef float v4f __attribute__((ext_vector_type(4)));

__device__ __forceinline__ v2f splat2(float s) { v2f r = {s, s}; return r; }

// ---------------------------------------------------------------------------
// Setup (K=8). P layout (stride 8):
//   P[0..7]   mu_k
//   P[8..15]  s1_k  = -0.5*log2(e)/v^2           (denom exponent scale)
//   P[16..23] lp_k  = log2(p_k)
//   P[24..31] ds_k  = (s2-s1)*ln2                 (ratio-poly argument scale)
//   P[32..39] c0_k  = C = 1/sqrt((p_k+eps)*(v+eps))
//   P[40..47] c2_k  = C/2
// Identity: exp2(s2*d^2+lw) = exp2(s1*d^2+lp) * C * e^u, u = ds*d^2 in [0,~0.15]
// e^u ~ quadratic Taylor (rel err <= u^3/6 ~ 5e-4, threshold is 0.1225).
// ---------------------------------------------------------------------------
__global__ void acn_setup(const float* __restrict__ mean,
                          const float* __restrict__ variance,
                          const float* __restrict__ prior,
                          float* __restrict__ P) {
    int lane = threadIdx.x;
    int k = lane & 7;
    float m  = mean[k];
    float va = variance[k];
    float p0 = prior[k];

    float v = logf(1.0f + expf(va));               // softplus
    float mx = p0;
    for (int off = 1; off < 8; off <<= 1) mx = fmaxf(mx, __shfl_xor(mx, off, 64));
    float e = expf(p0 - mx);
    float sum = e;
    for (int off = 1; off < 8; off <<= 1) sum += __shfl_xor(sum, off, 64);
    float pk = e / sum;

    float s1 = -0.5f * ACN_LOG2E / (v * v);
    float ve = v + ACN_EPS;
    float s2 = -0.5f * ACN_LOG2E / (ve * ve);
    float lp = log2f(pk);
    float C  = 1.0f / sqrtf((pk + ACN_EPS) * ve);
    float ds = (s2 - s1) * ACN_LN2;

    if (lane < 8) {
        P[k]      = m;
        P[8 + k]  = s1;
        P[16 + k] = lp;
        P[24 + k] = ds;
        P[32 + k] = C;
        P[40 + k] = C * 0.5f;
    }
}

// ---------------------------------------------------------------------------
// Packed-f32 core: processes 2 elements (one v2f) against all 8 components.
// Per k: 9 v_pk_* + 2 v_exp_f32.
// ---------------------------------------------------------------------------
__device__ __forceinline__ v2f acn_v2(v2f X,
                                      const float* mu, const float* s1,
                                      const float* lp, const float* ds,
                                      const float* c0, const float* c2) {
    v2f den = {0.0f, 0.0f};
    v2f S   = {0.0f, 0.0f};
#pragma unroll
    for (int k = 0; k < 8; ++k) {
        v2f d   = X - splat2(mu[k]);                                   // pk
        v2f d2  = d * d;                                               // pk
        v2f arg = __builtin_elementwise_fma(splat2(s1[k]), d2, splat2(lp[k])); // pk
        v2f E;
        E.x = __builtin_amdgcn_exp2f(arg.x);                           // trans
        E.y = __builtin_amdgcn_exp2f(arg.y);                           // trans
        den += E;                                                      // pk
        v2f u = splat2(ds[k]) * d2;                                    // pk
        v2f q = __builtin_elementwise_fma(u, splat2(c2[k]), splat2(c0[k])); // pk
        q     = __builtin_elementwise_fma(q, u, splat2(c0[k]));        // pk
        S     = __builtin_elementwise_fma(E * d, q, S);                // pk, pk
    }
    v2f r;
    r.x = S.x * __builtin_amdgcn_rcpf(den.x + ACN_EPS);
    r.y = S.y * __builtin_amdgcn_rcpf(den.y + ACN_EPS);
    return r;
}

__device__ __forceinline__ v4f acn_v4(v4f X,
                                      const float* mu, const float* s1,
                                      const float* lp, const float* ds,
                                      const float* c0, const float* c2) {
    v2f lo = {X.x, X.y}, hi = {X.z, X.w};
    v2f rl = acn_v2(lo, mu, s1, lp, ds, c0, c2);
    v2f rh = acn_v2(hi, mu, s1, lp, ds, c0, c2);
    v4f r = {rl.x, rl.y, rh.x, rh.y};
    return r;
}

// ---------------------------------------------------------------------------
// Main. Fast path (n4 == 8*T): 4 pair-iterations per thread with a 2-deep
// software pipeline — the next pair's loads issue before the current pair's
// compute, keeping 4 global_load_dwordx4 in flight.
// ---------------------------------------------------------------------------
__global__ __launch_bounds__(256) void acn_main(const v4f* __restrict__ x,
                                                v4f* __restrict__ out,
                                                const float* __restrict__ P,
                                                int n4) {
    float mu[8], s1[8], lp[8], ds[8], c0[8], c2[8];
#pragma unroll
    for (int k = 0; k < 8; ++k) {
        mu[k] = P[k];
        s1[k] = P[8 + k];
        lp[k] = P[16 + k];
        ds[k] = P[24 + k];
        c0[k] = P[32 + k];
        c2[k] = P[40 + k];
    }

    const int T   = gridDim.x * blockDim.x;
    const int idx = blockIdx.x * blockDim.x + threadIdx.x;

    if (n4 == 8 * T) {
        v4f a = x[idx];
        v4f b = x[idx + T];
#pragma unroll
        for (int c = 0; c < 4; ++c) {
            const int i = idx + c * 2 * T;
            v4f an, bn;
            if (c < 3) {                       // prefetch next pair
                an = x[i + 2 * T];
                bn = x[i + 3 * T];
            }
            __builtin_nontemporal_store(acn_v4(a, mu, s1, lp, ds, c0, c2), &out[i]);
            __builtin_nontemporal_store(acn_v4(b, mu, s1, lp, ds, c0, c2), &out[i + T]);
            if (c < 3) { a = an; b = bn; }
        }
    } else {
        for (int i = idx; i < n4; i += T) {
            __builtin_nontemporal_store(acn_v4(x[i], mu, s1, lp, ds, c0, c2), &out[i]);
        }
    }
}

extern "C" void kernel_launch(void* const* d_in, const int* in_sizes, int n_in,
                              void* d_out, int out_size, void* d_ws, size_t ws_size,
                              hipStream_t stream) {
    const float* x        = (const float*)d_in[0];
    const float* mean     = (const float*)d_in[1];
    const float* variance = (const float*)d_in[2];
    const float* prior    = (const float*)d_in[3];
    float* out = (float*)d_out;
    float* P   = (float*)d_ws;   // 48 floats of per-component constants

    acn_setup<<<1, 64, 0, stream>>>(mean, variance, prior, P);

    int n4 = out_size / 4;       // 4,194,304 = 8 * (2048*256)
    const int block = 256;
    const int grid  = 2048;      // T = 524288; fast path: 4 pipelined pair-iters
    acn_main<<<grid, block, 0, stream>>>((const v4f*)x, (v4f*)out, P, n4);
}